// Round 1
// baseline (230.922 us; speedup 1.0000x reference)
//
#include <hip/hip_runtime.h>
#include <math.h>

#define S_DIM 8
#define N_RES 256
#define MSA_DIM 256
#define PAIR_DIM 128
#define D_DIM 32
#define H_DIM 8
#define M_ROWS (S_DIM * N_RES)      // 2048
#define QKV_N (3 * H_DIM * D_DIM)   // 768
#define HD (H_DIM * D_DIM)          // 256

// ---------------- Kernel 1: LayerNorm of msa rows -> x [2048,256] ----------
__global__ __launch_bounds__(256) void ln_msa_kernel(
    const float* __restrict__ msa, const float* __restrict__ w,
    const float* __restrict__ b, float* __restrict__ x)
{
    int row = blockIdx.x;
    int t = threadIdx.x;
    float v = msa[row * MSA_DIM + t];
    float s1 = v, s2 = v * v;
#pragma unroll
    for (int m = 32; m >= 1; m >>= 1) {
        s1 += __shfl_xor(s1, m, 64);
        s2 += __shfl_xor(s2, m, 64);
    }
    __shared__ float r1[4], r2[4];
    int wave = t >> 6, lane = t & 63;
    if (lane == 0) { r1[wave] = s1; r2[wave] = s2; }
    __syncthreads();
    float S1 = r1[0] + r1[1] + r1[2] + r1[3];
    float S2 = r2[0] + r2[1] + r2[2] + r2[3];
    float mu = S1 * (1.0f / 256.0f);
    float var = S2 * (1.0f / 256.0f) - mu * mu;
    float rs = rsqrtf(var + 1e-5f);
    x[row * MSA_DIM + t] = (v - mu) * rs * w[t] + b[t];
}

// ---------------- Kernel 2: generic tiled SGEMM C = X[2048,256] @ W[256,N] --
// mode 0: scatter qkv -> q_t/k_t/v_t  [h][m][d]
// mode 1: sigmoid -> g_t [h][m][d]
// mode 2: + bias -> out [m][256]
__global__ __launch_bounds__(256) void gemm_tile_kernel(
    const float* __restrict__ X, const float* __restrict__ W,
    const float* __restrict__ bias, float* __restrict__ o0,
    float* __restrict__ o1, float* __restrict__ o2, int Ncols, int mode)
{
    __shared__ float Xs[16][64 + 1];
    __shared__ float Ws[16][64];
    int t = threadIdx.x;
    int m0 = blockIdx.y * 64, n0 = blockIdx.x * 64;
    int tm = t >> 4, tn = t & 15;
    int lxm = t >> 2, lxk = (t & 3) * 4;    // X loader
    int lwk = t >> 4, lwn = (t & 15) * 4;   // W loader
    float acc[4][4] = {};
    for (int k0 = 0; k0 < 256; k0 += 16) {
        float4 xa = *(const float4*)&X[(m0 + lxm) * 256 + k0 + lxk];
        float4 wa = *(const float4*)&W[(k0 + lwk) * Ncols + n0 + lwn];
        __syncthreads();
        Xs[lxk + 0][lxm] = xa.x; Xs[lxk + 1][lxm] = xa.y;
        Xs[lxk + 2][lxm] = xa.z; Xs[lxk + 3][lxm] = xa.w;
        *(float4*)&Ws[lwk][lwn] = wa;
        __syncthreads();
#pragma unroll
        for (int kk = 0; kk < 16; kk++) {
            float a0 = Xs[kk][tm * 4 + 0], a1 = Xs[kk][tm * 4 + 1];
            float a2 = Xs[kk][tm * 4 + 2], a3 = Xs[kk][tm * 4 + 3];
            float4 b4 = *(const float4*)&Ws[kk][tn * 4];
            acc[0][0] += a0 * b4.x; acc[0][1] += a0 * b4.y; acc[0][2] += a0 * b4.z; acc[0][3] += a0 * b4.w;
            acc[1][0] += a1 * b4.x; acc[1][1] += a1 * b4.y; acc[1][2] += a1 * b4.z; acc[1][3] += a1 * b4.w;
            acc[2][0] += a2 * b4.x; acc[2][1] += a2 * b4.y; acc[2][2] += a2 * b4.z; acc[2][3] += a2 * b4.w;
            acc[3][0] += a3 * b4.x; acc[3][1] += a3 * b4.y; acc[3][2] += a3 * b4.z; acc[3][3] += a3 * b4.w;
        }
    }
#pragma unroll
    for (int ii = 0; ii < 4; ii++) {
#pragma unroll
        for (int jj = 0; jj < 4; jj++) {
            float c = acc[ii][jj];
            int mm = m0 + tm * 4 + ii;
            int nn = n0 + tn * 4 + jj;
            if (mode == 0) {
                int chunk = nn >> 8, r = nn & 255, d = r >> 3, h = r & 7;
                float* dst = (chunk == 0) ? o0 : ((chunk == 1) ? o1 : o2);
                dst[(h * M_ROWS + mm) * D_DIM + d] = c;
            } else if (mode == 1) {
                int d = nn >> 3, h = nn & 7;
                o0[(h * M_ROWS + mm) * D_DIM + d] = 1.0f / (1.0f + __expf(-c));
            } else {
                o0[mm * 256 + nn] = c + bias[nn];
            }
        }
    }
}

// ---------------- Kernel 3: pair bias b2[h][i][j] = LN(pair[i,j,:]) @ w_b ---
__global__ __launch_bounds__(256) void pair_bias_kernel(
    const float* __restrict__ pair, const float* __restrict__ lw,
    const float* __restrict__ lb, const float* __restrict__ wb,
    float* __restrict__ b2)
{
    __shared__ float wbt[8][128];   // transposed w_b for conflict-free reads
    int t = threadIdx.x;
    for (int idx = t; idx < 1024; idx += 256) {
        int c = idx >> 3, h = idx & 7;
        wbt[h][c] = wb[idx];
    }
    __syncthreads();
    int wave = t >> 6, lane = t & 63;
    int row = blockIdx.x * 4 + wave;               // (i,j) flat, 0..65535
    const float* in = pair + (size_t)row * PAIR_DIM;
    float x0 = in[lane], x1 = in[lane + 64];
    float s1 = x0 + x1, s2 = x0 * x0 + x1 * x1;
#pragma unroll
    for (int m = 1; m < 64; m <<= 1) {
        s1 += __shfl_xor(s1, m, 64);
        s2 += __shfl_xor(s2, m, 64);
    }
    float mu = s1 * (1.0f / 128.0f);
    float var = s2 * (1.0f / 128.0f) - mu * mu;
    float rs = rsqrtf(var + 1e-5f);
    float xn0 = (x0 - mu) * rs * lw[lane] + lb[lane];
    float xn1 = (x1 - mu) * rs * lw[lane + 64] + lb[lane + 64];
#pragma unroll
    for (int h = 0; h < 8; h++) {
        float a = xn0 * wbt[h][lane] + xn1 * wbt[h][lane + 64];
#pragma unroll
        for (int m = 1; m < 64; m <<= 1) a += __shfl_xor(a, m, 64);
        if (lane == h) b2[h * 65536 + row] = a;
    }
}

// ---------------- Kernel 4: per-channel softmax attention + gate -----------
// block = (s, h, i_tile of 32); 512 blocks x 256 threads; K/V staged in LDS
__global__ __launch_bounds__(256) void attn_kernel(
    const float* __restrict__ q_t, const float* __restrict__ k_t,
    const float* __restrict__ v_t, const float* __restrict__ g_t,
    const float* __restrict__ b2, float* __restrict__ ao)
{
    __shared__ float k_sh[256][32];
    __shared__ float v_sh[256][32];
    int blk = blockIdx.x;
    int s = blk >> 6, h = (blk >> 3) & 7, it = blk & 7;
    int t = threadIdx.x;
    const float* kb = k_t + (size_t)(h * M_ROWS + s * N_RES) * D_DIM;
    const float* vb = v_t + (size_t)(h * M_ROWS + s * N_RES) * D_DIM;
    for (int idx = t; idx < 2048; idx += 256) {
        ((float4*)k_sh)[idx] = ((const float4*)kb)[idx];
        ((float4*)v_sh)[idx] = ((const float4*)vb)[idx];
    }
    __syncthreads();
    int li = t >> 3, dg = t & 7, d0 = dg * 4;
    int ig = it * 32 + li;                  // global residue index i
    int mrow = s * N_RES + ig;
    const float SCALE = 0.17677669529663687f;  // 1/sqrt(32)
    float4 q4 = *(const float4*)&q_t[(size_t)(h * M_ROWS + mrow) * D_DIM + d0];
    float qs0 = q4.x * SCALE, qs1 = q4.y * SCALE, qs2 = q4.z * SCALE, qs3 = q4.w * SCALE;
    float den0 = 0, den1 = 0, den2 = 0, den3 = 0;
    float acc0 = 0, acc1 = 0, acc2 = 0, acc3 = 0;
    const float* brow = b2 + h * 65536 + ig * 256;
    for (int j0 = 0; j0 < 256; j0 += 4) {
        float4 bb = *(const float4*)&brow[j0];
#pragma unroll
        for (int jj = 0; jj < 4; jj++) {
            int j = j0 + jj;
            float bj = (jj == 0) ? bb.x : (jj == 1) ? bb.y : (jj == 2) ? bb.z : bb.w;
            float4 k4 = *(const float4*)&k_sh[j][d0];
            float4 v4 = *(const float4*)&v_sh[j][d0];
            float e0 = __expf(qs0 * k4.x + bj); den0 += e0; acc0 += e0 * v4.x;
            float e1 = __expf(qs1 * k4.y + bj); den1 += e1; acc1 += e1 * v4.y;
            float e2 = __expf(qs2 * k4.z + bj); den2 += e2; acc2 += e2 * v4.z;
            float e3 = __expf(qs3 * k4.w + bj); den3 += e3; acc3 += e3 * v4.w;
        }
    }
    float4 g4 = *(const float4*)&g_t[(size_t)(h * M_ROWS + mrow) * D_DIM + d0];
    float* orow = ao + (size_t)mrow * HD;
    orow[(d0 + 0) * 8 + h] = g4.x * acc0 / den0;
    orow[(d0 + 1) * 8 + h] = g4.y * acc1 / den1;
    orow[(d0 + 2) * 8 + h] = g4.z * acc2 / den2;
    orow[(d0 + 3) * 8 + h] = g4.w * acc3 / den3;
}

extern "C" void kernel_launch(void* const* d_in, const int* in_sizes, int n_in,
                              void* d_out, int out_size, void* d_ws, size_t ws_size,
                              hipStream_t stream)
{
    const float* msa_rep   = (const float*)d_in[0];
    const float* pair_rep  = (const float*)d_in[1];
    const float* ln_w      = (const float*)d_in[2];
    const float* ln_b      = (const float*)d_in[3];
    const float* w_qkv     = (const float*)d_in[4];
    const float* ln_pair_w = (const float*)d_in[5];
    const float* ln_pair_b = (const float*)d_in[6];
    const float* w_b       = (const float*)d_in[7];
    const float* w_g       = (const float*)d_in[8];
    const float* w_out     = (const float*)d_in[9];
    const float* b_out     = (const float*)d_in[10];
    float* out = (float*)d_out;

    float* ws = (float*)d_ws;
    const size_t CH = 524288;     // 2048*256
    float* x   = ws + 0 * CH;
    float* q_t = ws + 1 * CH;
    float* k_t = ws + 2 * CH;
    float* v_t = ws + 3 * CH;
    float* g_t = ws + 4 * CH;
    float* b2  = ws + 5 * CH;
    float* ao  = ws + 6 * CH;

    ln_msa_kernel<<<M_ROWS, 256, 0, stream>>>(msa_rep, ln_w, ln_b, x);

    gemm_tile_kernel<<<dim3(QKV_N / 64, M_ROWS / 64), 256, 0, stream>>>(
        x, w_qkv, b_out, q_t, k_t, v_t, QKV_N, 0);

    gemm_tile_kernel<<<dim3(HD / 64, M_ROWS / 64), 256, 0, stream>>>(
        x, w_g, b_out, g_t, g_t, g_t, HD, 1);

    pair_bias_kernel<<<65536 / 4, 256, 0, stream>>>(
        pair_rep, ln_pair_w, ln_pair_b, w_b, b2);

    attn_kernel<<<512, 256, 0, stream>>>(q_t, k_t, v_t, g_t, b2, ao);

    gemm_tile_kernel<<<dim3(HD / 64, M_ROWS / 64), 256, 0, stream>>>(
        ao, w_out, b_out, out, out, out, HD, 2);
}

// Round 2
// 194.944 us; speedup vs baseline: 1.1846x; 1.1846x over previous
//
#include <hip/hip_runtime.h>
#include <math.h>

#define S_DIM 8
#define N_RES 256
#define MSA_DIM 256
#define PAIR_DIM 128
#define D_DIM 32
#define H_DIM 8
#define M_ROWS (S_DIM * N_RES)      // 2048
#define QKV_N (3 * H_DIM * D_DIM)   // 768
#define HD (H_DIM * D_DIM)          // 256

// ---- wave64 sum via DPP (rocPRIM canonical sequence); total lands in lane 63
__device__ __forceinline__ float dpp_add(float x, float y) { return x + y; }

#define DPP_ADD(x, ctrl, rmask)                                                \
    x += __int_as_float(__builtin_amdgcn_update_dpp(                           \
        0, __float_as_int(x), (ctrl), (rmask), 0xf, true))

__device__ __forceinline__ float wave_sum63(float x) {
    DPP_ADD(x, 0x111, 0xf);   // row_shr:1
    DPP_ADD(x, 0x112, 0xf);   // row_shr:2
    DPP_ADD(x, 0x114, 0xf);   // row_shr:4
    DPP_ADD(x, 0x118, 0xf);   // row_shr:8
    DPP_ADD(x, 0x142, 0xa);   // row_bcast:15 -> rows 1,3
    DPP_ADD(x, 0x143, 0xc);   // row_bcast:31 -> rows 2,3
    return x;                 // lane 63 holds the wave total
}

// ---------------- Kernel 1: LayerNorm of msa rows -> x [2048,256] ----------
__global__ __launch_bounds__(256) void ln_msa_kernel(
    const float* __restrict__ msa, const float* __restrict__ w,
    const float* __restrict__ b, float* __restrict__ x)
{
    int row = blockIdx.x;
    int t = threadIdx.x;
    float v = msa[row * MSA_DIM + t];
    float s1 = wave_sum63(v);
    float s2 = wave_sum63(v * v);
    __shared__ float r1[4], r2[4];
    int wave = t >> 6, lane = t & 63;
    if (lane == 63) { r1[wave] = s1; r2[wave] = s2; }
    __syncthreads();
    float S1 = r1[0] + r1[1] + r1[2] + r1[3];
    float S2 = r2[0] + r2[1] + r2[2] + r2[3];
    float mu = S1 * (1.0f / 256.0f);
    float var = S2 * (1.0f / 256.0f) - mu * mu;
    float rs = rsqrtf(var + 1e-5f);
    x[row * MSA_DIM + t] = (v - mu) * rs * w[t] + b[t];
}

// ---------------- Kernel 2: generic tiled SGEMM C = X[2048,256] @ W[256,N] --
// mode 0: scatter qkv -> q_t/k_t/v_t  [h][m][d]
// mode 1: sigmoid -> g_t [h][m][d]
// mode 2: + bias -> out [m][256]
__global__ __launch_bounds__(256) void gemm_tile_kernel(
    const float* __restrict__ X, const float* __restrict__ W,
    const float* __restrict__ bias, float* __restrict__ o0,
    float* __restrict__ o1, float* __restrict__ o2, int Ncols, int mode)
{
    // Xs stride 68: keeps 16B alignment (68*4=272=17*16) AND float4 rows;
    // a4 read addresses depend only on tm (4 addrs/wave -> broadcast, no conflict)
    __shared__ float Xs[16][68];
    __shared__ float Ws[16][64];
    int t = threadIdx.x;
    int m0 = blockIdx.y * 64, n0 = blockIdx.x * 64;
    int tm = t >> 4, tn = t & 15;
    int lxm = t >> 2, lxk = (t & 3) * 4;    // X loader
    int lwk = t >> 4, lwn = (t & 15) * 4;   // W loader
    float acc[4][4] = {};
    for (int k0 = 0; k0 < 256; k0 += 16) {
        float4 xa = *(const float4*)&X[(m0 + lxm) * 256 + k0 + lxk];
        float4 wa = *(const float4*)&W[(k0 + lwk) * Ncols + n0 + lwn];
        __syncthreads();
        Xs[lxk + 0][lxm] = xa.x; Xs[lxk + 1][lxm] = xa.y;
        Xs[lxk + 2][lxm] = xa.z; Xs[lxk + 3][lxm] = xa.w;
        *(float4*)&Ws[lwk][lwn] = wa;
        __syncthreads();
#pragma unroll
        for (int kk = 0; kk < 16; kk++) {
            float4 a4 = *(const float4*)&Xs[kk][tm * 4];
            float4 b4 = *(const float4*)&Ws[kk][tn * 4];
            acc[0][0] += a4.x * b4.x; acc[0][1] += a4.x * b4.y; acc[0][2] += a4.x * b4.z; acc[0][3] += a4.x * b4.w;
            acc[1][0] += a4.y * b4.x; acc[1][1] += a4.y * b4.y; acc[1][2] += a4.y * b4.z; acc[1][3] += a4.y * b4.w;
            acc[2][0] += a4.z * b4.x; acc[2][1] += a4.z * b4.y; acc[2][2] += a4.z * b4.z; acc[2][3] += a4.z * b4.w;
            acc[3][0] += a4.w * b4.x; acc[3][1] += a4.w * b4.y; acc[3][2] += a4.w * b4.z; acc[3][3] += a4.w * b4.w;
        }
    }
#pragma unroll
    for (int ii = 0; ii < 4; ii++) {
#pragma unroll
        for (int jj = 0; jj < 4; jj++) {
            float c = acc[ii][jj];
            int mm = m0 + tm * 4 + ii;
            int nn = n0 + tn * 4 + jj;
            if (mode == 0) {
                int chunk = nn >> 8, r = nn & 255, d = r >> 3, h = r & 7;
                float* dst = (chunk == 0) ? o0 : ((chunk == 1) ? o1 : o2);
                dst[(h * M_ROWS + mm) * D_DIM + d] = c;
            } else if (mode == 1) {
                int d = nn >> 3, h = nn & 7;
                o0[(h * M_ROWS + mm) * D_DIM + d] = 1.0f / (1.0f + __expf(-c));
            } else {
                o0[mm * 256 + nn] = c + bias[nn];
            }
        }
    }
}

// ---------------- Kernel 3: pair bias b2[h][i][j] = LN(pair[i,j,:]) @ w_b ---
// 1 wave per row; ALL reductions via DPP (no ds_swizzle)
__global__ __launch_bounds__(256) void pair_bias_kernel(
    const float* __restrict__ pair, const float* __restrict__ lw,
    const float* __restrict__ lb, const float* __restrict__ wb,
    float* __restrict__ b2)
{
    __shared__ float wbt[8][128];   // transposed w_b
    int t = threadIdx.x;
    for (int idx = t; idx < 1024; idx += 256) {
        int c = idx >> 3, h = idx & 7;
        wbt[h][c] = wb[idx];
    }
    __syncthreads();
    int wave = t >> 6, lane = t & 63;
    int row = blockIdx.x * 4 + wave;               // (i,j) flat, 0..65535
    const float* in = pair + (size_t)row * PAIR_DIM;
    float x0 = in[lane], x1 = in[lane + 64];
    float s1 = wave_sum63(x0 + x1);
    float s2 = wave_sum63(x0 * x0 + x1 * x1);
    float S1 = __int_as_float(__builtin_amdgcn_readlane(__float_as_int(s1), 63));
    float S2 = __int_as_float(__builtin_amdgcn_readlane(__float_as_int(s2), 63));
    float mu = S1 * (1.0f / 128.0f);
    float var = S2 * (1.0f / 128.0f) - mu * mu;
    float rs = rsqrtf(var + 1e-5f);
    float xn0 = (x0 - mu) * rs * lw[lane] + lb[lane];
    float xn1 = (x1 - mu) * rs * lw[lane + 64] + lb[lane + 64];
    float ah[8];
#pragma unroll
    for (int h = 0; h < 8; h++) {
        float a = xn0 * wbt[h][lane] + xn1 * wbt[h][lane + 64];
        ah[h] = wave_sum63(a);
    }
    if (lane == 63) {
#pragma unroll
        for (int h = 0; h < 8; h++) b2[h * 65536 + row] = ah[h];
    }
}

// ---------------- Kernel 4: per-channel softmax attention + gate -----------
// block = (s, h, i_tile of 32); 512 blocks x 256 threads; K/V staged in LDS
__global__ __launch_bounds__(256) void attn_kernel(
    const float* __restrict__ q_t, const float* __restrict__ k_t,
    const float* __restrict__ v_t, const float* __restrict__ g_t,
    const float* __restrict__ b2, float* __restrict__ ao)
{
    __shared__ float k_sh[256][32];
    __shared__ float v_sh[256][32];
    int blk = blockIdx.x;
    int s = blk >> 6, h = (blk >> 3) & 7, it = blk & 7;
    int t = threadIdx.x;
    const float* kb = k_t + (size_t)(h * M_ROWS + s * N_RES) * D_DIM;
    const float* vb = v_t + (size_t)(h * M_ROWS + s * N_RES) * D_DIM;
    for (int idx = t; idx < 2048; idx += 256) {
        ((float4*)k_sh)[idx] = ((const float4*)kb)[idx];
        ((float4*)v_sh)[idx] = ((const float4*)vb)[idx];
    }
    __syncthreads();
    int li = t >> 3, dg = t & 7, d0 = dg * 4;
    int ig = it * 32 + li;                  // global residue index i
    int mrow = s * N_RES + ig;
    const float SCALE = 0.17677669529663687f;  // 1/sqrt(32)
    float4 q4 = *(const float4*)&q_t[(size_t)(h * M_ROWS + mrow) * D_DIM + d0];
    float qs0 = q4.x * SCALE, qs1 = q4.y * SCALE, qs2 = q4.z * SCALE, qs3 = q4.w * SCALE;
    float den0 = 0, den1 = 0, den2 = 0, den3 = 0;
    float acc0 = 0, acc1 = 0, acc2 = 0, acc3 = 0;
    const float* brow = b2 + h * 65536 + ig * 256;
    for (int j0 = 0; j0 < 256; j0 += 4) {
        float4 bb = *(const float4*)&brow[j0];
#pragma unroll
        for (int jj = 0; jj < 4; jj++) {
            int j = j0 + jj;
            float bj = (jj == 0) ? bb.x : (jj == 1) ? bb.y : (jj == 2) ? bb.z : bb.w;
            float4 k4 = *(const float4*)&k_sh[j][d0];
            float4 v4 = *(const float4*)&v_sh[j][d0];
            float e0 = __expf(qs0 * k4.x + bj); den0 += e0; acc0 += e0 * v4.x;
            float e1 = __expf(qs1 * k4.y + bj); den1 += e1; acc1 += e1 * v4.y;
            float e2 = __expf(qs2 * k4.z + bj); den2 += e2; acc2 += e2 * v4.z;
            float e3 = __expf(qs3 * k4.w + bj); den3 += e3; acc3 += e3 * v4.w;
        }
    }
    float4 g4 = *(const float4*)&g_t[(size_t)(h * M_ROWS + mrow) * D_DIM + d0];
    float* orow = ao + (size_t)mrow * HD;
    orow[(d0 + 0) * 8 + h] = g4.x * acc0 / den0;
    orow[(d0 + 1) * 8 + h] = g4.y * acc1 / den1;
    orow[(d0 + 2) * 8 + h] = g4.z * acc2 / den2;
    orow[(d0 + 3) * 8 + h] = g4.w * acc3 / den3;
}

extern "C" void kernel_launch(void* const* d_in, const int* in_sizes, int n_in,
                              void* d_out, int out_size, void* d_ws, size_t ws_size,
                              hipStream_t stream)
{
    const float* msa_rep   = (const float*)d_in[0];
    const float* pair_rep  = (const float*)d_in[1];
    const float* ln_w      = (const float*)d_in[2];
    const float* ln_b      = (const float*)d_in[3];
    const float* w_qkv     = (const float*)d_in[4];
    const float* ln_pair_w = (const float*)d_in[5];
    const float* ln_pair_b = (const float*)d_in[6];
    const float* w_b       = (const float*)d_in[7];
    const float* w_g       = (const float*)d_in[8];
    const float* w_out     = (const float*)d_in[9];
    const float* b_out     = (const float*)d_in[10];
    float* out = (float*)d_out;

    float* ws = (float*)d_ws;
    const size_t CH = 524288;     // 2048*256
    float* x   = ws + 0 * CH;
    float* q_t = ws + 1 * CH;
    float* k_t = ws + 2 * CH;
    float* v_t = ws + 3 * CH;
    float* g_t = ws + 4 * CH;
    float* b2  = ws + 5 * CH;
    float* ao  = ws + 6 * CH;

    ln_msa_kernel<<<M_ROWS, 256, 0, stream>>>(msa_rep, ln_w, ln_b, x);

    gemm_tile_kernel<<<dim3(QKV_N / 64, M_ROWS / 64), 256, 0, stream>>>(
        x, w_qkv, b_out, q_t, k_t, v_t, QKV_N, 0);

    gemm_tile_kernel<<<dim3(HD / 64, M_ROWS / 64), 256, 0, stream>>>(
        x, w_g, b_out, g_t, g_t, g_t, HD, 1);

    pair_bias_kernel<<<65536 / 4, 256, 0, stream>>>(
        pair_rep, ln_pair_w, ln_pair_b, w_b, b2);

    attn_kernel<<<512, 256, 0, stream>>>(q_t, k_t, v_t, g_t, b2, ao);

    gemm_tile_kernel<<<dim3(HD / 64, M_ROWS / 64), 256, 0, stream>>>(
        ao, w_out, b_out, out, out, out, HD, 2);
}

// Round 3
// 175.476 us; speedup vs baseline: 1.3160x; 1.1109x over previous
//
#include <hip/hip_runtime.h>
#include <math.h>

#define S_DIM 8
#define N_RES 256
#define MSA_DIM 256
#define PAIR_DIM 128
#define D_DIM 32
#define H_DIM 8
#define M_ROWS (S_DIM * N_RES)      // 2048
#define QKV_N (3 * H_DIM * D_DIM)   // 768
#define HD (H_DIM * D_DIM)          // 256

// ---- wave64 sum via DPP; total lands in lane 63
#define DPP_ADD(x, ctrl, rmask)                                                \
    x += __int_as_float(__builtin_amdgcn_update_dpp(                           \
        0, __float_as_int(x), (ctrl), (rmask), 0xf, true))

__device__ __forceinline__ float wave_sum63(float x) {
    DPP_ADD(x, 0x111, 0xf);   // row_shr:1
    DPP_ADD(x, 0x112, 0xf);   // row_shr:2
    DPP_ADD(x, 0x114, 0xf);   // row_shr:4
    DPP_ADD(x, 0x118, 0xf);   // row_shr:8
    DPP_ADD(x, 0x142, 0xa);   // row_bcast:15 -> rows 1,3
    DPP_ADD(x, 0x143, 0xc);   // row_bcast:31 -> rows 2,3
    return x;                 // lane 63 holds the wave total
}

// sum over the 4 lanes of a quad (all quad lanes end with the total)
__device__ __forceinline__ float quad_sum(float x) {
    x += __int_as_float(__builtin_amdgcn_update_dpp(
        0, __float_as_int(x), 0xB1, 0xf, 0xf, true));  // quad_perm [1,0,3,2]
    x += __int_as_float(__builtin_amdgcn_update_dpp(
        0, __float_as_int(x), 0x4E, 0xf, 0xf, true));  // quad_perm [2,3,0,1]
    return x;
}

// ---------------- Kernel 1: LayerNorm of msa rows -> x [2048,256] ----------
__global__ __launch_bounds__(256) void ln_msa_kernel(
    const float* __restrict__ msa, const float* __restrict__ w,
    const float* __restrict__ b, float* __restrict__ x)
{
    int row = blockIdx.x;
    int t = threadIdx.x;
    float v = msa[row * MSA_DIM + t];
    float s1 = wave_sum63(v);
    float s2 = wave_sum63(v * v);
    __shared__ float r1[4], r2[4];
    int wave = t >> 6, lane = t & 63;
    if (lane == 63) { r1[wave] = s1; r2[wave] = s2; }
    __syncthreads();
    float S1 = r1[0] + r1[1] + r1[2] + r1[3];
    float S2 = r2[0] + r2[1] + r2[2] + r2[3];
    float mu = S1 * (1.0f / 256.0f);
    float var = S2 * (1.0f / 256.0f) - mu * mu;
    float rs = rsqrtf(var + 1e-5f);
    x[row * MSA_DIM + t] = (v - mu) * rs * w[t] + b[t];
}

// ------- Kernel 2: fused qkv+g GEMM: C = X[2048,256] @ {w_qkv | w_g} -------
// blockIdx.x < 12 -> qkv columns (scatter to q_t/k_t/v_t [h][m][d])
// blockIdx.x >= 12 -> gate columns (sigmoid -> g_t [h][m][d])
__global__ __launch_bounds__(256) void xw_kernel(
    const float* __restrict__ X, const float* __restrict__ Wqkv,
    const float* __restrict__ Wg, float* __restrict__ q_t,
    float* __restrict__ k_t, float* __restrict__ v_t, float* __restrict__ g_t)
{
    __shared__ float Xs[16][68];
    __shared__ float Ws[16][64];
    int t = threadIdx.x;
    int bx = blockIdx.x;
    int qkv_mode = (bx < 12);
    const float* W = qkv_mode ? Wqkv : Wg;
    int Ncols = qkv_mode ? QKV_N : HD;
    int n0 = qkv_mode ? bx * 64 : (bx - 12) * 64;
    int m0 = blockIdx.y * 64;
    int tm = t >> 4, tn = t & 15;
    int lxm = t >> 2, lxk = (t & 3) * 4;
    int lwk = t >> 4, lwn = (t & 15) * 4;
    float acc[4][4] = {};
    for (int k0 = 0; k0 < 256; k0 += 16) {
        float4 xa = *(const float4*)&X[(m0 + lxm) * 256 + k0 + lxk];
        float4 wa = *(const float4*)&W[(k0 + lwk) * Ncols + n0 + lwn];
        __syncthreads();
        Xs[lxk + 0][lxm] = xa.x; Xs[lxk + 1][lxm] = xa.y;
        Xs[lxk + 2][lxm] = xa.z; Xs[lxk + 3][lxm] = xa.w;
        *(float4*)&Ws[lwk][lwn] = wa;
        __syncthreads();
#pragma unroll
        for (int kk = 0; kk < 16; kk++) {
            float4 a4 = *(const float4*)&Xs[kk][tm * 4];
            float4 b4 = *(const float4*)&Ws[kk][tn * 4];
            acc[0][0] += a4.x * b4.x; acc[0][1] += a4.x * b4.y; acc[0][2] += a4.x * b4.z; acc[0][3] += a4.x * b4.w;
            acc[1][0] += a4.y * b4.x; acc[1][1] += a4.y * b4.y; acc[1][2] += a4.y * b4.z; acc[1][3] += a4.y * b4.w;
            acc[2][0] += a4.z * b4.x; acc[2][1] += a4.z * b4.y; acc[2][2] += a4.z * b4.z; acc[2][3] += a4.z * b4.w;
            acc[3][0] += a4.w * b4.x; acc[3][1] += a4.w * b4.y; acc[3][2] += a4.w * b4.z; acc[3][3] += a4.w * b4.w;
        }
    }
#pragma unroll
    for (int ii = 0; ii < 4; ii++) {
#pragma unroll
        for (int jj = 0; jj < 4; jj++) {
            float c = acc[ii][jj];
            int mm = m0 + tm * 4 + ii;
            int nn = n0 + tn * 4 + jj;
            if (qkv_mode) {
                int chunk = nn >> 8, r = nn & 255, d = r >> 3, h = r & 7;
                float* dst = (chunk == 0) ? q_t : ((chunk == 1) ? k_t : v_t);
                dst[(h * M_ROWS + mm) * D_DIM + d] = c;
            } else {
                int d = nn >> 3, h = nn & 7;
                g_t[(h * M_ROWS + mm) * D_DIM + d] = 1.0f / (1.0f + __expf(-c));
            }
        }
    }
}

// ------- Kernel 2b: out GEMM: out = ao[2048, hd-layout h*32+d] @ w_out + b --
// w_out row for ao-column k (h=k>>5, d=k&31) is (d*8+h) -> permuted row fetch
__global__ __launch_bounds__(256) void out_gemm_kernel(
    const float* __restrict__ X, const float* __restrict__ W,
    const float* __restrict__ bias, float* __restrict__ out)
{
    __shared__ float Xs[16][68];
    __shared__ float Ws[16][64];
    int t = threadIdx.x;
    int m0 = blockIdx.y * 64, n0 = blockIdx.x * 64;
    int tm = t >> 4, tn = t & 15;
    int lxm = t >> 2, lxk = (t & 3) * 4;
    int lwk = t >> 4, lwn = (t & 15) * 4;
    float acc[4][4] = {};
    for (int k0 = 0; k0 < 256; k0 += 16) {
        int k = k0 + lwk;
        int wrow = (k & 31) * 8 + (k >> 5);   // ao-layout -> w_out row
        float4 xa = *(const float4*)&X[(m0 + lxm) * 256 + k0 + lxk];
        float4 wa = *(const float4*)&W[wrow * 256 + n0 + lwn];
        __syncthreads();
        Xs[lxk + 0][lxm] = xa.x; Xs[lxk + 1][lxm] = xa.y;
        Xs[lxk + 2][lxm] = xa.z; Xs[lxk + 3][lxm] = xa.w;
        *(float4*)&Ws[lwk][lwn] = wa;
        __syncthreads();
#pragma unroll
        for (int kk = 0; kk < 16; kk++) {
            float4 a4 = *(const float4*)&Xs[kk][tm * 4];
            float4 b4 = *(const float4*)&Ws[kk][tn * 4];
            acc[0][0] += a4.x * b4.x; acc[0][1] += a4.x * b4.y; acc[0][2] += a4.x * b4.z; acc[0][3] += a4.x * b4.w;
            acc[1][0] += a4.y * b4.x; acc[1][1] += a4.y * b4.y; acc[1][2] += a4.y * b4.z; acc[1][3] += a4.y * b4.w;
            acc[2][0] += a4.z * b4.x; acc[2][1] += a4.z * b4.y; acc[2][2] += a4.z * b4.z; acc[2][3] += a4.z * b4.w;
            acc[3][0] += a4.w * b4.x; acc[3][1] += a4.w * b4.y; acc[3][2] += a4.w * b4.z; acc[3][3] += a4.w * b4.w;
        }
    }
#pragma unroll
    for (int ii = 0; ii < 4; ii++) {
#pragma unroll
        for (int jj = 0; jj < 4; jj++) {
            int mm = m0 + tm * 4 + ii;
            int nn = n0 + tn * 4 + jj;
            out[mm * 256 + nn] = acc[ii][jj] + bias[nn];
        }
    }
}

// ---------------- Kernel 3: pair bias b2[h][i][j] = LN(pair[i,j,:]) @ w_b ---
__global__ __launch_bounds__(256) void pair_bias_kernel(
    const float* __restrict__ pair, const float* __restrict__ lw,
    const float* __restrict__ lb, const float* __restrict__ wb,
    float* __restrict__ b2)
{
    __shared__ float wbt[8][128];
    int t = threadIdx.x;
    for (int idx = t; idx < 1024; idx += 256) {
        int c = idx >> 3, h = idx & 7;
        wbt[h][c] = wb[idx];
    }
    __syncthreads();
    int wave = t >> 6, lane = t & 63;
    int row = blockIdx.x * 4 + wave;
    const float* in = pair + (size_t)row * PAIR_DIM;
    float x0 = in[lane], x1 = in[lane + 64];
    float s1 = wave_sum63(x0 + x1);
    float s2 = wave_sum63(x0 * x0 + x1 * x1);
    float S1 = __int_as_float(__builtin_amdgcn_readlane(__float_as_int(s1), 63));
    float S2 = __int_as_float(__builtin_amdgcn_readlane(__float_as_int(s2), 63));
    float mu = S1 * (1.0f / 128.0f);
    float var = S2 * (1.0f / 128.0f) - mu * mu;
    float rs = rsqrtf(var + 1e-5f);
    float xn0 = (x0 - mu) * rs * lw[lane] + lb[lane];
    float xn1 = (x1 - mu) * rs * lw[lane + 64] + lb[lane + 64];
    float ah[8];
#pragma unroll
    for (int h = 0; h < 8; h++) {
        float a = xn0 * wbt[h][lane] + xn1 * wbt[h][lane + 64];
        ah[h] = wave_sum63(a);
    }
    if (lane == 63) {
#pragma unroll
        for (int h = 0; h < 8; h++) b2[h * 65536 + row] = ah[h];
    }
}

// ---------------- Kernel 4: per-channel softmax attention + gate -----------
// thread = (jp in 4, dg in 8, li in 8): 4 i's x 4 d's = 16 channels,
// j-loop split 4-way over jp; quad DPP reduce at the end.
// ao stored as [m][h*32+d] (float4 stores); out-GEMM permutes W rows.
__global__ __launch_bounds__(256) void attn_kernel(
    const float* __restrict__ q_t, const float* __restrict__ k_t,
    const float* __restrict__ v_t, const float* __restrict__ g_t,
    const float* __restrict__ b2, float* __restrict__ ao)
{
    __shared__ float k_sh[256][32];
    __shared__ float v_sh[256][32];
    int blk = blockIdx.x;
    int s = blk >> 6, h = (blk >> 3) & 7, it = blk & 7;
    int t = threadIdx.x;
    const float* kb = k_t + (size_t)(h * M_ROWS + s * N_RES) * D_DIM;
    const float* vb = v_t + (size_t)(h * M_ROWS + s * N_RES) * D_DIM;
    for (int idx = t; idx < 2048; idx += 256) {
        ((float4*)k_sh)[idx] = ((const float4*)kb)[idx];
        ((float4*)v_sh)[idx] = ((const float4*)vb)[idx];
    }
    __syncthreads();
    int jp = t & 3, dg = (t >> 2) & 7, li = t >> 5;
    int d0 = dg * 4;
    const float SCALE = 0.17677669529663687f;   // 1/sqrt(32)
    int ig[4], mrow[4];
    float qs[4][4];
#pragma unroll
    for (int r = 0; r < 4; r++) {
        ig[r] = it * 32 + r * 8 + li;
        mrow[r] = s * N_RES + ig[r];
        float4 q4 = *(const float4*)&q_t[(size_t)(h * M_ROWS + mrow[r]) * D_DIM + d0];
        qs[r][0] = q4.x * SCALE; qs[r][1] = q4.y * SCALE;
        qs[r][2] = q4.z * SCALE; qs[r][3] = q4.w * SCALE;
    }
    float den[4][4] = {}, acc[4][4] = {};
    const float* bbase = b2 + h * 65536;
    for (int js4 = 0; js4 < 16; js4++) {
        float bb[4][4];
#pragma unroll
        for (int r = 0; r < 4; r++)
            *(float4*)&bb[r][0] =
                *(const float4*)&bbase[ig[r] * 256 + jp * 64 + js4 * 4];
#pragma unroll
        for (int u = 0; u < 4; u++) {
            int j = jp * 64 + js4 * 4 + u;
            float ka[4], va[4];
            *(float4*)ka = *(const float4*)&k_sh[j][d0];
            *(float4*)va = *(const float4*)&v_sh[j][d0];
#pragma unroll
            for (int r = 0; r < 4; r++) {
#pragma unroll
                for (int c = 0; c < 4; c++) {
                    float e = __expf(qs[r][c] * ka[c] + bb[r][u]);
                    den[r][c] += e;
                    acc[r][c] += e * va[c];
                }
            }
        }
    }
#pragma unroll
    for (int r = 0; r < 4; r++)
#pragma unroll
        for (int c = 0; c < 4; c++) {
            den[r][c] = quad_sum(den[r][c]);
            acc[r][c] = quad_sum(acc[r][c]);
        }
    if (jp == 0) {
#pragma unroll
        for (int r = 0; r < 4; r++) {
            float4 g4 = *(const float4*)&g_t[(size_t)(h * M_ROWS + mrow[r]) * D_DIM + d0];
            float4 o;
            o.x = g4.x * acc[r][0] / den[r][0];
            o.y = g4.y * acc[r][1] / den[r][1];
            o.z = g4.z * acc[r][2] / den[r][2];
            o.w = g4.w * acc[r][3] / den[r][3];
            *(float4*)&ao[(size_t)mrow[r] * HD + h * 32 + d0] = o;
        }
    }
}

extern "C" void kernel_launch(void* const* d_in, const int* in_sizes, int n_in,
                              void* d_out, int out_size, void* d_ws, size_t ws_size,
                              hipStream_t stream)
{
    const float* msa_rep   = (const float*)d_in[0];
    const float* pair_rep  = (const float*)d_in[1];
    const float* ln_w      = (const float*)d_in[2];
    const float* ln_b      = (const float*)d_in[3];
    const float* w_qkv     = (const float*)d_in[4];
    const float* ln_pair_w = (const float*)d_in[5];
    const float* ln_pair_b = (const float*)d_in[6];
    const float* w_b       = (const float*)d_in[7];
    const float* w_g       = (const float*)d_in[8];
    const float* w_out     = (const float*)d_in[9];
    const float* b_out     = (const float*)d_in[10];
    float* out = (float*)d_out;

    float* ws = (float*)d_ws;
    const size_t CH = 524288;     // 2048*256
    float* x   = ws + 0 * CH;
    float* q_t = ws + 1 * CH;
    float* k_t = ws + 2 * CH;
    float* v_t = ws + 3 * CH;
    float* g_t = ws + 4 * CH;
    float* b2  = ws + 5 * CH;
    float* ao  = ws + 6 * CH;

    ln_msa_kernel<<<M_ROWS, 256, 0, stream>>>(msa_rep, ln_w, ln_b, x);

    xw_kernel<<<dim3(16, M_ROWS / 64), 256, 0, stream>>>(
        x, w_qkv, w_g, q_t, k_t, v_t, g_t);

    pair_bias_kernel<<<65536 / 4, 256, 0, stream>>>(
        pair_rep, ln_pair_w, ln_pair_b, w_b, b2);

    attn_kernel<<<512, 256, 0, stream>>>(q_t, k_t, v_t, g_t, b2, ao);

    out_gemm_kernel<<<dim3(HD / 64, M_ROWS / 64), 256, 0, stream>>>(
        ao, w_out, b_out, out);
}

// Round 4
// 170.439 us; speedup vs baseline: 1.3549x; 1.0296x over previous
//
#include <hip/hip_runtime.h>
#include <math.h>

#define S_DIM 8
#define N_RES 256
#define MSA_DIM 256
#define PAIR_DIM 128
#define D_DIM 32
#define H_DIM 8
#define M_ROWS (S_DIM * N_RES)      // 2048
#define QKV_N (3 * H_DIM * D_DIM)   // 768
#define HD (H_DIM * D_DIM)          // 256
#define LOG2E 1.4426950408889634f

// ---- wave64 sum via DPP; total lands in lane 63
#define DPP_ADD(x, ctrl, rmask)                                                \
    x += __int_as_float(__builtin_amdgcn_update_dpp(                           \
        0, __float_as_int(x), (ctrl), (rmask), 0xf, true))

__device__ __forceinline__ float wave_sum63(float x) {
    DPP_ADD(x, 0x111, 0xf);   // row_shr:1
    DPP_ADD(x, 0x112, 0xf);   // row_shr:2
    DPP_ADD(x, 0x114, 0xf);   // row_shr:4
    DPP_ADD(x, 0x118, 0xf);   // row_shr:8
    DPP_ADD(x, 0x142, 0xa);   // row_bcast:15 -> rows 1,3
    DPP_ADD(x, 0x143, 0xc);   // row_bcast:31 -> rows 2,3
    return x;
}

// sum over the 4 lanes of a quad (all quad lanes end with the total)
__device__ __forceinline__ float quad_sum(float x) {
    x += __int_as_float(__builtin_amdgcn_update_dpp(
        0, __float_as_int(x), 0xB1, 0xf, 0xf, true));  // quad_perm [1,0,3,2]
    x += __int_as_float(__builtin_amdgcn_update_dpp(
        0, __float_as_int(x), 0x4E, 0xf, 0xf, true));  // quad_perm [2,3,0,1]
    return x;
}

// ---------------- Kernel 1: LayerNorm of msa rows -> x [2048,256] ----------
__global__ __launch_bounds__(256) void ln_msa_kernel(
    const float* __restrict__ msa, const float* __restrict__ w,
    const float* __restrict__ b, float* __restrict__ x)
{
    int row = blockIdx.x;
    int t = threadIdx.x;
    float v = msa[row * MSA_DIM + t];
    float s1 = wave_sum63(v);
    float s2 = wave_sum63(v * v);
    __shared__ float r1[4], r2[4];
    int wave = t >> 6, lane = t & 63;
    if (lane == 63) { r1[wave] = s1; r2[wave] = s2; }
    __syncthreads();
    float S1 = r1[0] + r1[1] + r1[2] + r1[3];
    float S2 = r2[0] + r2[1] + r2[2] + r2[3];
    float mu = S1 * (1.0f / 256.0f);
    float var = S2 * (1.0f / 256.0f) - mu * mu;
    float rs = rsqrtf(var + 1e-5f);
    x[row * MSA_DIM + t] = (v - mu) * rs * w[t] + b[t];
}

// ------- Kernel 2: fused qkv+g GEMM: C = X[2048,256] @ {w_qkv | w_g} -------
__global__ __launch_bounds__(256) void xw_kernel(
    const float* __restrict__ X, const float* __restrict__ Wqkv,
    const float* __restrict__ Wg, float* __restrict__ q_t,
    float* __restrict__ k_t, float* __restrict__ v_t, float* __restrict__ g_t)
{
    __shared__ float Xs[16][68];
    __shared__ float Ws[16][64];
    int t = threadIdx.x;
    int bx = blockIdx.x;
    int qkv_mode = (bx < 12);
    const float* W = qkv_mode ? Wqkv : Wg;
    int Ncols = qkv_mode ? QKV_N : HD;
    int n0 = qkv_mode ? bx * 64 : (bx - 12) * 64;
    int m0 = blockIdx.y * 64;
    int tm = t >> 4, tn = t & 15;
    int lxm = t >> 2, lxk = (t & 3) * 4;
    int lwk = t >> 4, lwn = (t & 15) * 4;
    float acc[4][4] = {};
    for (int k0 = 0; k0 < 256; k0 += 16) {
        float4 xa = *(const float4*)&X[(m0 + lxm) * 256 + k0 + lxk];
        float4 wa = *(const float4*)&W[(k0 + lwk) * Ncols + n0 + lwn];
        __syncthreads();
        Xs[lxk + 0][lxm] = xa.x; Xs[lxk + 1][lxm] = xa.y;
        Xs[lxk + 2][lxm] = xa.z; Xs[lxk + 3][lxm] = xa.w;
        *(float4*)&Ws[lwk][lwn] = wa;
        __syncthreads();
#pragma unroll
        for (int kk = 0; kk < 16; kk++) {
            float4 a4 = *(const float4*)&Xs[kk][tm * 4];
            float4 b4 = *(const float4*)&Ws[kk][tn * 4];
            acc[0][0] += a4.x * b4.x; acc[0][1] += a4.x * b4.y; acc[0][2] += a4.x * b4.z; acc[0][3] += a4.x * b4.w;
            acc[1][0] += a4.y * b4.x; acc[1][1] += a4.y * b4.y; acc[1][2] += a4.y * b4.z; acc[1][3] += a4.y * b4.w;
            acc[2][0] += a4.z * b4.x; acc[2][1] += a4.z * b4.y; acc[2][2] += a4.z * b4.z; acc[2][3] += a4.z * b4.w;
            acc[3][0] += a4.w * b4.x; acc[3][1] += a4.w * b4.y; acc[3][2] += a4.w * b4.z; acc[3][3] += a4.w * b4.w;
        }
    }
#pragma unroll
    for (int ii = 0; ii < 4; ii++) {
#pragma unroll
        for (int jj = 0; jj < 4; jj++) {
            float c = acc[ii][jj];
            int mm = m0 + tm * 4 + ii;
            int nn = n0 + tn * 4 + jj;
            if (qkv_mode) {
                int chunk = nn >> 8, r = nn & 255, d = r >> 3, h = r & 7;
                float* dst = (chunk == 0) ? q_t : ((chunk == 1) ? k_t : v_t);
                dst[(h * M_ROWS + mm) * D_DIM + d] = c;
            } else {
                int d = nn >> 3, h = nn & 7;
                g_t[(h * M_ROWS + mm) * D_DIM + d] = 1.0f / (1.0f + __expf(-c));
            }
        }
    }
}

// ------- Kernel 2b: out GEMM: out = ao[2048, hd-layout h*32+d] @ w_out + b --
__global__ __launch_bounds__(256) void out_gemm_kernel(
    const float* __restrict__ X, const float* __restrict__ W,
    const float* __restrict__ bias, float* __restrict__ out)
{
    __shared__ float Xs[16][68];
    __shared__ float Ws[16][64];
    int t = threadIdx.x;
    int m0 = blockIdx.y * 64, n0 = blockIdx.x * 64;
    int tm = t >> 4, tn = t & 15;
    int lxm = t >> 2, lxk = (t & 3) * 4;
    int lwk = t >> 4, lwn = (t & 15) * 4;
    float acc[4][4] = {};
    for (int k0 = 0; k0 < 256; k0 += 16) {
        int k = k0 + lwk;
        int wrow = (k & 31) * 8 + (k >> 5);   // ao-layout -> w_out row
        float4 xa = *(const float4*)&X[(m0 + lxm) * 256 + k0 + lxk];
        float4 wa = *(const float4*)&W[wrow * 256 + n0 + lwn];
        __syncthreads();
        Xs[lxk + 0][lxm] = xa.x; Xs[lxk + 1][lxm] = xa.y;
        Xs[lxk + 2][lxm] = xa.z; Xs[lxk + 3][lxm] = xa.w;
        *(float4*)&Ws[lwk][lwn] = wa;
        __syncthreads();
#pragma unroll
        for (int kk = 0; kk < 16; kk++) {
            float4 a4 = *(const float4*)&Xs[kk][tm * 4];
            float4 b4 = *(const float4*)&Ws[kk][tn * 4];
            acc[0][0] += a4.x * b4.x; acc[0][1] += a4.x * b4.y; acc[0][2] += a4.x * b4.z; acc[0][3] += a4.x * b4.w;
            acc[1][0] += a4.y * b4.x; acc[1][1] += a4.y * b4.y; acc[1][2] += a4.y * b4.z; acc[1][3] += a4.y * b4.w;
            acc[2][0] += a4.z * b4.x; acc[2][1] += a4.z * b4.y; acc[2][2] += a4.z * b4.z; acc[2][3] += a4.z * b4.w;
            acc[3][0] += a4.w * b4.x; acc[3][1] += a4.w * b4.y; acc[3][2] += a4.w * b4.z; acc[3][3] += a4.w * b4.w;
        }
    }
#pragma unroll
    for (int ii = 0; ii < 4; ii++) {
#pragma unroll
        for (int jj = 0; jj < 4; jj++) {
            int mm = m0 + tm * 4 + ii;
            int nn = n0 + tn * 4 + jj;
            out[mm * 256 + nn] = acc[ii][jj] + bias[nn];
        }
    }
}

// ------- Kernel 3a: setup A'[c][h]=lw*wb*log2e [128][12], S'[8], C'[8] -----
__global__ __launch_bounds__(128) void pb_setup_kernel(
    const float* __restrict__ lw, const float* __restrict__ lb,
    const float* __restrict__ wb, float* __restrict__ Abuf)
{
    __shared__ float P[128][8], Q[128][8];
    int c = threadIdx.x;
    float lwc = lw[c], lbc = lb[c];
#pragma unroll
    for (int h = 0; h < 8; h++) {
        float w = wb[c * 8 + h];
        float a = lwc * w;
        P[c][h] = a;
        Q[c][h] = lbc * w;
        Abuf[c * 12 + h] = a * LOG2E;
    }
    __syncthreads();
    if (c < 8) {
        float s = 0, cc = 0;
        for (int k = 0; k < 128; k++) { s += P[k][c]; cc += Q[k][c]; }
        Abuf[1536 + c] = s * LOG2E;     // S'
        Abuf[1544 + c] = cc * LOG2E;    // C'
    }
}

// ------- Kernel 3b: pair bias b2[h][i][j] = log2e*(LN(pair[i,j,:]) @ w_b) --
// 4 lanes/row (quad q owns c in {16*it+4q+k}); 64 rows/block; A' in LDS.
__global__ __launch_bounds__(256) void pair_bias_kernel(
    const float* __restrict__ pair, const float* __restrict__ Abuf,
    float* __restrict__ b2)
{
    __shared__ __align__(16) float As[1552];   // [128][12] + S'[8] + C'[8]
    int t = threadIdx.x;
    for (int idx = t; idx < 388; idx += 256)
        ((float4*)As)[idx] = ((const float4*)Abuf)[idx];
    __syncthreads();
    int row = blockIdx.x * 64 + (t >> 2);
    int q = t & 3;
    const float* in = pair + (size_t)row * PAIR_DIM;
    float4 x4[8];
#pragma unroll
    for (int it = 0; it < 8; it++)
        x4[it] = *(const float4*)&in[it * 16 + q * 4];
    float s = 0, s2 = 0;
    float dot[8] = {};
#pragma unroll
    for (int it = 0; it < 8; it++) {
        float xk[4];
        *(float4*)xk = x4[it];
#pragma unroll
        for (int k = 0; k < 4; k++) {
            int c = it * 16 + q * 4 + k;
            float xv = xk[k];
            s += xv; s2 += xv * xv;
            float4 A0 = *(const float4*)&As[c * 12];
            float4 A1 = *(const float4*)&As[c * 12 + 4];
            dot[0] += xv * A0.x; dot[1] += xv * A0.y;
            dot[2] += xv * A0.z; dot[3] += xv * A0.w;
            dot[4] += xv * A1.x; dot[5] += xv * A1.y;
            dot[6] += xv * A1.z; dot[7] += xv * A1.w;
        }
    }
    s = quad_sum(s);
    s2 = quad_sum(s2);
#pragma unroll
    for (int h = 0; h < 8; h++) dot[h] = quad_sum(dot[h]);
    float mu = s * (1.0f / 128.0f);
    float var = s2 * (1.0f / 128.0f) - mu * mu;
    float rs = rsqrtf(var + 1e-5f);
    int h0 = q * 2;
#pragma unroll
    for (int u = 0; u < 2; u++) {
        int h = h0 + u;
        b2[h * 65536 + row] = rs * (dot[h] - mu * As[1536 + h]) + As[1544 + h];
    }
}

// ---------------- Kernel 4: per-channel softmax attention + gate -----------
// b2 is pre-scaled by log2e; qs folds SCALE*log2e; raw v_exp_f32 via exp2.
__global__ __launch_bounds__(256) void attn_kernel(
    const float* __restrict__ q_t, const float* __restrict__ k_t,
    const float* __restrict__ v_t, const float* __restrict__ g_t,
    const float* __restrict__ b2, float* __restrict__ ao)
{
    __shared__ float k_sh[256][32];
    __shared__ float v_sh[256][32];
    int blk = blockIdx.x;
    int s = blk >> 6, h = (blk >> 3) & 7, it = blk & 7;
    int t = threadIdx.x;
    const float* kb = k_t + (size_t)(h * M_ROWS + s * N_RES) * D_DIM;
    const float* vb = v_t + (size_t)(h * M_ROWS + s * N_RES) * D_DIM;
    for (int idx = t; idx < 2048; idx += 256) {
        ((float4*)k_sh)[idx] = ((const float4*)kb)[idx];
        ((float4*)v_sh)[idx] = ((const float4*)vb)[idx];
    }
    __syncthreads();
    int jp = t & 3, dg = (t >> 2) & 7, li = t >> 5;
    int d0 = dg * 4;
    const float SCL2 = 0.17677669529663687f * LOG2E;  // 1/sqrt(32) * log2e
    int ig[4], mrow[4];
    float qs[4][4];
#pragma unroll
    for (int r = 0; r < 4; r++) {
        ig[r] = it * 32 + r * 8 + li;
        mrow[r] = s * N_RES + ig[r];
        float4 q4 = *(const float4*)&q_t[(size_t)(h * M_ROWS + mrow[r]) * D_DIM + d0];
        qs[r][0] = q4.x * SCL2; qs[r][1] = q4.y * SCL2;
        qs[r][2] = q4.z * SCL2; qs[r][3] = q4.w * SCL2;
    }
    float den[4][4] = {}, acc[4][4] = {};
    const float* bbase = b2 + h * 65536;
    for (int js4 = 0; js4 < 16; js4++) {
        float bb[4][4];
#pragma unroll
        for (int r = 0; r < 4; r++)
            *(float4*)&bb[r][0] =
                *(const float4*)&bbase[ig[r] * 256 + jp * 64 + js4 * 4];
#pragma unroll
        for (int u = 0; u < 4; u++) {
            int j = jp * 64 + js4 * 4 + u;
            float ka[4], va[4];
            *(float4*)ka = *(const float4*)&k_sh[j][d0];
            *(float4*)va = *(const float4*)&v_sh[j][d0];
#pragma unroll
            for (int r = 0; r < 4; r++) {
#pragma unroll
                for (int c = 0; c < 4; c++) {
                    float e = __builtin_amdgcn_exp2f(qs[r][c] * ka[c] + bb[r][u]);
                    den[r][c] += e;
                    acc[r][c] += e * va[c];
                }
            }
        }
    }
#pragma unroll
    for (int r = 0; r < 4; r++)
#pragma unroll
        for (int c = 0; c < 4; c++) {
            den[r][c] = quad_sum(den[r][c]);
            acc[r][c] = quad_sum(acc[r][c]);
        }
    if (jp == 0) {
#pragma unroll
        for (int r = 0; r < 4; r++) {
            float4 g4 = *(const float4*)&g_t[(size_t)(h * M_ROWS + mrow[r]) * D_DIM + d0];
            float4 o;
            o.x = g4.x * acc[r][0] / den[r][0];
            o.y = g4.y * acc[r][1] / den[r][1];
            o.z = g4.z * acc[r][2] / den[r][2];
            o.w = g4.w * acc[r][3] / den[r][3];
            *(float4*)&ao[(size_t)mrow[r] * HD + h * 32 + d0] = o;
        }
    }
}

extern "C" void kernel_launch(void* const* d_in, const int* in_sizes, int n_in,
                              void* d_out, int out_size, void* d_ws, size_t ws_size,
                              hipStream_t stream)
{
    const float* msa_rep   = (const float*)d_in[0];
    const float* pair_rep  = (const float*)d_in[1];
    const float* ln_w      = (const float*)d_in[2];
    const float* ln_b      = (const float*)d_in[3];
    const float* w_qkv     = (const float*)d_in[4];
    const float* ln_pair_w = (const float*)d_in[5];
    const float* ln_pair_b = (const float*)d_in[6];
    const float* w_b       = (const float*)d_in[7];
    const float* w_g       = (const float*)d_in[8];
    const float* w_out     = (const float*)d_in[9];
    const float* b_out     = (const float*)d_in[10];
    float* out = (float*)d_out;

    float* ws = (float*)d_ws;
    const size_t CH = 524288;     // 2048*256
    float* x    = ws + 0 * CH;
    float* q_t  = ws + 1 * CH;
    float* k_t  = ws + 2 * CH;
    float* v_t  = ws + 3 * CH;
    float* g_t  = ws + 4 * CH;
    float* b2   = ws + 5 * CH;
    float* ao   = ws + 6 * CH;
    float* Abuf = ws + 7 * CH;    // 1552 floats

    ln_msa_kernel<<<M_ROWS, 256, 0, stream>>>(msa_rep, ln_w, ln_b, x);

    xw_kernel<<<dim3(16, M_ROWS / 64), 256, 0, stream>>>(
        x, w_qkv, w_g, q_t, k_t, v_t, g_t);

    pb_setup_kernel<<<1, 128, 0, stream>>>(ln_pair_w, ln_pair_b, w_b, Abuf);

    pair_bias_kernel<<<65536 / 64, 256, 0, stream>>>(pair_rep, Abuf, b2);

    attn_kernel<<<512, 256, 0, stream>>>(q_t, k_t, v_t, g_t, b2, ao);

    out_gemm_kernel<<<dim3(HD / 64, M_ROWS / 64), 256, 0, stream>>>(
        ao, w_out, b_out, out);
}